// Round 14
// baseline (134.170 us; speedup 1.0000x reference)
//
#include <hip/hip_runtime.h>
#include <hip/hip_fp16.h>

#define D 32
#define BSHIFT 8            // 256 nodes per bucket
#define BNODES 256
#define NB_MAX 512
#define CHUNK 4096
#define CTHREADS 512

union H8 {                  // 8 halves <-> 16 bytes
    float4 f4;
    __half2 h2[4];
};

// multisplit scatter into PADDED bucket regions.
// bcursor[] is zero-initialized; region base tid*cap added here.
__global__ void scatter_bucket(const int* __restrict__ src, const int* __restrict__ dst,
                               int* __restrict__ bcursor, unsigned int* __restrict__ staged,
                               int n_edges, int cap) {
    __shared__ int cnt[NB_MAX];
    __shared__ int sbase[NB_MAX];
    __shared__ int gbase[NB_MAX];
    __shared__ unsigned int stg[CHUNK];
    __shared__ unsigned short stgb[CHUNK];
    int tid = threadIdx.x;
    for (int j = tid; j < NB_MAX; j += CTHREADS) cnt[j] = 0;
    __syncthreads();
    int base = blockIdx.x * CHUNK;
    const int EPT = CHUNK / CTHREADS;  // 8
    int b8[EPT], r8[EPT], s8[EPT], d8[EPT];
    #pragma unroll
    for (int k = 0; k < EPT; ++k) {
        int i = base + k * CTHREADS + tid;
        if (i < n_edges) {
            int dv = dst[i];
            s8[k] = src[i];
            d8[k] = dv & (BNODES - 1);
            b8[k] = dv >> BSHIFT;
            r8[k] = atomicAdd(&cnt[b8[k]], 1);
        } else {
            b8[k] = -1;
        }
    }
    __syncthreads();
    int v = cnt[tid];
    sbase[tid] = v;
    __syncthreads();
    for (int off = 1; off < NB_MAX; off <<= 1) {
        int t = (tid >= off) ? sbase[tid - off] : 0;
        __syncthreads();
        sbase[tid] += t;
        __syncthreads();
    }
    int excl = sbase[tid] - v;
    __syncthreads();
    sbase[tid] = excl;
    gbase[tid] = v ? (tid * cap + atomicAdd(&bcursor[tid], v)) : 0;
    __syncthreads();
    #pragma unroll
    for (int k = 0; k < EPT; ++k) {
        if (b8[k] >= 0) {
            int p = sbase[b8[k]] + r8[k];
            stg[p] = ((unsigned)s8[k] << BSHIFT) | (unsigned)d8[k];
            stgb[p] = (unsigned short)b8[k];
        }
    }
    __syncthreads();
    int valid = n_edges - base;
    if (valid > CHUNK) valid = CHUNK;
    for (int j = tid; j < valid; j += CTHREADS) {
        int b = stgb[j];
        int idx = gbase[b] + (j - sbase[b]);
        if (idx < (b + 1) * cap)  // safety guard (statistically never taken)
            staged[idx] = stg[j];
    }
}

// Fused: per-bucket degree count -> local scan -> meta {start,end,dinv2,dsq},
// counting sort into padded csr region, and s0 = fp16(feat*dinv) init.
__global__ void bucket_finalize(const int* __restrict__ bcursor, const unsigned int* __restrict__ staged,
                                int cap, int* __restrict__ csr, float4* __restrict__ meta,
                                const float* __restrict__ feat, __half* __restrict__ s0,
                                int n_nodes) {
    __shared__ int cnt[BNODES];
    __shared__ int scn[BNODES];
    __shared__ int cursor[BNODES];
    __shared__ float ldinv[BNODES];
    int tid = threadIdx.x;
    int b = blockIdx.x;
    int node0 = b << BSHIFT;
    int nn = n_nodes - node0;
    if (nn > BNODES) nn = BNODES;
    int base = b * cap;
    int m = bcursor[b];        // count written by scatter
    if (m > cap) m = cap;
    if (tid < BNODES) cnt[tid] = 0;
    __syncthreads();
    for (int j = tid; j < m; j += CTHREADS)
        atomicAdd(&cnt[staged[base + j] & (BNODES - 1)], 1);
    __syncthreads();
    if (tid < BNODES) scn[tid] = cnt[tid];
    __syncthreads();
    for (int off = 1; off < BNODES; off <<= 1) {
        int t = 0;
        if (tid < BNODES && tid >= off) t = scn[tid - off];
        __syncthreads();
        if (tid < BNODES) scn[tid] += t;
        __syncthreads();
    }
    if (tid < BNODES) {
        int excl = scn[tid] - cnt[tid];
        cursor[tid] = excl;
        if (tid < nn) {
            float fd = (float)cnt[tid];
            fd = fd < 1.0f ? 1.0f : fd;
            float dn = rsqrtf(fd);
            ldinv[tid] = dn;
            float4 mt;
            mt.x = __int_as_float(base + excl);
            mt.y = __int_as_float(base + excl + cnt[tid]);
            mt.z = dn * dn;
            mt.w = sqrtf(fd);
            meta[node0 + tid] = mt;
        }
    }
    __syncthreads();
    // counting sort into padded csr region
    for (int j = tid; j < m; j += CTHREADS) {
        unsigned int p = staged[base + j];
        int d = p & (BNODES - 1);
        int pos = atomicAdd(&cursor[d], 1);
        csr[base + pos] = (int)(p >> BSHIFT);
    }
    // fused init: s0 rows for this bucket's nodes (8 features per task)
    int ntask = nn * 4;
    for (int t = tid; t < ntask; t += CTHREADS) {
        int nl = t >> 2;
        int q8 = (t & 3) << 3;
        float dn = ldinv[nl];
        size_t off = ((size_t)(node0 + nl) << 5) + q8;
        float4 a = *reinterpret_cast<const float4*>(&feat[off]);
        float4 bb = *reinterpret_cast<const float4*>(&feat[off + 4]);
        H8 o;
        o.h2[0] = __floats2half2_rn(a.x * dn, a.y * dn);
        o.h2[1] = __floats2half2_rn(a.z * dn, a.w * dn);
        o.h2[2] = __floats2half2_rn(bb.x * dn, bb.y * dn);
        o.h2[3] = __floats2half2_rn(bb.z * dn, bb.w * dn);
        *reinterpret_cast<float4*>(&s0[off]) = o.f4;
    }
}

__device__ __forceinline__ void add_row(const __half* __restrict__ tab, int sn, int q8, float* a) {
    H8 u;
    u.f4 = *reinterpret_cast<const float4*>(&tab[((size_t)sn << 5) + q8]);
    float2 p0 = __half22float2(u.h2[0]);
    float2 p1 = __half22float2(u.h2[1]);
    float2 p2 = __half22float2(u.h2[2]);
    float2 p3 = __half22float2(u.h2[3]);
    a[0] += p0.x; a[1] += p0.y; a[2] += p1.x; a[3] += p1.y;
    a[4] += p2.x; a[5] += p2.y; a[6] += p3.x; a[7] += p3.y;
}

// 8-deep gather: issue all 8 csr loads, then all 8 row loads, then accumulate
// in the same sequential order (bitwise-identical sums vs 4-deep).
__device__ __forceinline__ void gather8(const __half* __restrict__ tab,
                                        const int* __restrict__ csr, int e, int q8, float* a) {
    int i0 = csr[e],     i1 = csr[e + 1], i2 = csr[e + 2], i3 = csr[e + 3];
    int i4 = csr[e + 4], i5 = csr[e + 5], i6 = csr[e + 6], i7 = csr[e + 7];
    H8 u0, u1, u2, u3, u4, u5, u6, u7;
    u0.f4 = *reinterpret_cast<const float4*>(&tab[((size_t)i0 << 5) + q8]);
    u1.f4 = *reinterpret_cast<const float4*>(&tab[((size_t)i1 << 5) + q8]);
    u2.f4 = *reinterpret_cast<const float4*>(&tab[((size_t)i2 << 5) + q8]);
    u3.f4 = *reinterpret_cast<const float4*>(&tab[((size_t)i3 << 5) + q8]);
    u4.f4 = *reinterpret_cast<const float4*>(&tab[((size_t)i4 << 5) + q8]);
    u5.f4 = *reinterpret_cast<const float4*>(&tab[((size_t)i5 << 5) + q8]);
    u6.f4 = *reinterpret_cast<const float4*>(&tab[((size_t)i6 << 5) + q8]);
    u7.f4 = *reinterpret_cast<const float4*>(&tab[((size_t)i7 << 5) + q8]);
    H8* us[8] = {&u0, &u1, &u2, &u3, &u4, &u5, &u6, &u7};
    #pragma unroll
    for (int k = 0; k < 8; ++k) {
        float2 p0 = __half22float2(us[k]->h2[0]);
        float2 p1 = __half22float2(us[k]->h2[1]);
        float2 p2 = __half22float2(us[k]->h2[2]);
        float2 p3 = __half22float2(us[k]->h2[3]);
        a[0] += p0.x; a[1] += p0.y; a[2] += p1.x; a[3] += p1.y;
        a[4] += p2.x; a[5] += p2.y; a[6] += p3.x; a[7] += p3.y;
    }
}

// 4 lanes/node, 8 features each, gather loop unrolled 8-deep.
// s_next = s_cur[node] - agg * dinv2[node]
__global__ void hop_kernel(const float4* __restrict__ meta, const int* __restrict__ csr,
                           const __half* __restrict__ s_cur, __half* __restrict__ s_next,
                           int n_nodes) {
    int t = blockIdx.x * blockDim.x + threadIdx.x;
    int node = t >> 2;
    if (node >= n_nodes) return;
    int q8 = (t & 3) << 3;
    float4 mt = meta[node];
    int e = __float_as_int(mt.x), end = __float_as_int(mt.y);
    float a[8] = {0.f, 0.f, 0.f, 0.f, 0.f, 0.f, 0.f, 0.f};
    for (; e + 7 < end; e += 8)
        gather8(s_cur, csr, e, q8, a);
    if (e + 3 < end) {
        int i0 = csr[e], i1 = csr[e + 1], i2 = csr[e + 2], i3 = csr[e + 3];
        add_row(s_cur, i0, q8, a);
        add_row(s_cur, i1, q8, a);
        add_row(s_cur, i2, q8, a);
        add_row(s_cur, i3, q8, a);
        e += 4;
    }
    for (; e < end; ++e)
        add_row(s_cur, csr[e], q8, a);
    size_t off = ((size_t)node << 5) + q8;
    float dn2 = mt.z;
    H8 sc;
    sc.f4 = *reinterpret_cast<const float4*>(&s_cur[off]);
    float2 c0 = __half22float2(sc.h2[0]);
    float2 c1 = __half22float2(sc.h2[1]);
    float2 c2 = __half22float2(sc.h2[2]);
    float2 c3 = __half22float2(sc.h2[3]);
    H8 so;
    so.h2[0] = __floats2half2_rn(c0.x - a[0] * dn2, c0.y - a[1] * dn2);
    so.h2[1] = __floats2half2_rn(c1.x - a[2] * dn2, c1.y - a[3] * dn2);
    so.h2[2] = __floats2half2_rn(c2.x - a[4] * dn2, c2.y - a[5] * dn2);
    so.h2[3] = __floats2half2_rn(c3.x - a[6] * dn2, c3.y - a[7] * dn2);
    *reinterpret_cast<float4*>(&s_next[off]) = so.f4;
}

// Last hop fused with combine: computes s4 in registers, then
// h = feat + dsq * (th1*s1 + th2*s2 + th3*s3 + th4*s4)
__global__ void hop_last_kernel(const float4* __restrict__ meta, const int* __restrict__ csr,
                                const __half* __restrict__ s1, const __half* __restrict__ s2,
                                const __half* __restrict__ s3, const float* __restrict__ feat,
                                float* __restrict__ h, int n_nodes) {
    int t = blockIdx.x * blockDim.x + threadIdx.x;
    int node = t >> 2;
    if (node >= n_nodes) return;
    int q8 = (t & 3) << 3;
    float4 mt = meta[node];
    int e = __float_as_int(mt.x), end = __float_as_int(mt.y);
    float a[8] = {0.f, 0.f, 0.f, 0.f, 0.f, 0.f, 0.f, 0.f};
    for (; e + 7 < end; e += 8)
        gather8(s3, csr, e, q8, a);
    if (e + 3 < end) {
        int i0 = csr[e], i1 = csr[e + 1], i2 = csr[e + 2], i3 = csr[e + 3];
        add_row(s3, i0, q8, a);
        add_row(s3, i1, q8, a);
        add_row(s3, i2, q8, a);
        add_row(s3, i3, q8, a);
        e += 4;
    }
    for (; e < end; ++e)
        add_row(s3, csr[e], q8, a);
    size_t off = ((size_t)node << 5) + q8;
    float dn2 = mt.z;
    float ds = mt.w;
    H8 u1, u2, u3;
    u1.f4 = *reinterpret_cast<const float4*>(&s1[off]);
    u2.f4 = *reinterpret_cast<const float4*>(&s2[off]);
    u3.f4 = *reinterpret_cast<const float4*>(&s3[off]);
    float4 fa = *reinterpret_cast<const float4*>(&feat[off]);
    float4 fb = *reinterpret_cast<const float4*>(&feat[off + 4]);
    const float th1 = -0.5f, th2 = 0.25f, th3 = -0.125f, th4 = 0.0625f;
    float r[8] = {fa.x, fa.y, fa.z, fa.w, fb.x, fb.y, fb.z, fb.w};
    #pragma unroll
    for (int j = 0; j < 4; ++j) {
        float2 p1 = __half22float2(u1.h2[j]);
        float2 p2 = __half22float2(u2.h2[j]);
        float2 p3 = __half22float2(u3.h2[j]);
        float s4x = p3.x - a[2 * j] * dn2;
        float s4y = p3.y - a[2 * j + 1] * dn2;
        float mx = fmaf(th1, p1.x, fmaf(th2, p2.x, fmaf(th3, p3.x, th4 * s4x)));
        float my = fmaf(th1, p1.y, fmaf(th2, p2.y, fmaf(th3, p3.y, th4 * s4y)));
        r[2 * j]     = fmaf(ds, mx, r[2 * j]);
        r[2 * j + 1] = fmaf(ds, my, r[2 * j + 1]);
    }
    float4 o0 = {r[0], r[1], r[2], r[3]};
    float4 o1 = {r[4], r[5], r[6], r[7]};
    *reinterpret_cast<float4*>(&h[off]) = o0;
    *reinterpret_cast<float4*>(&h[off + 4]) = o1;
}

extern "C" void kernel_launch(void* const* d_in, const int* in_sizes, int n_in,
                              void* d_out, int out_size, void* d_ws, size_t ws_size,
                              hipStream_t stream) {
    const float* feat = (const float*)d_in[0];
    const int*   src  = (const int*)d_in[1];
    const int*   dst  = (const int*)d_in[2];
    float* h = (float*)d_out;

    int n_nodes = in_sizes[0] / D;
    int n_edges = in_sizes[1];
    long long total_nf = (long long)n_nodes * D;
    int nb = (n_nodes + BNODES - 1) >> BSHIFT;
    int cap = (int)(((2LL * n_edges / nb) + 1023) & ~1023LL);

    // workspace layout (16B-aligned)
    char* w = (char*)d_ws;
    auto alloc = [&](size_t bytes) {
        char* p = w;
        w += (bytes + 15) & ~(size_t)15;
        return (void*)p;
    };
    int*          bcursor = (int*)alloc(NB_MAX * 4);
    float4*       meta    = (float4*)alloc((size_t)n_nodes * 16);
    unsigned int* staged  = (unsigned int*)alloc((size_t)nb * cap * 4);
    int*          csr     = (int*)alloc((size_t)nb * cap * 4);
    __half*       s[4];
    for (int k = 0; k < 4; ++k) s[k] = (__half*)alloc((size_t)total_nf * 2);

    hipMemsetAsync(bcursor, 0, NB_MAX * sizeof(int), stream);
    int eblocks = (n_edges + CHUNK - 1) / CHUNK;
    scatter_bucket<<<eblocks, CTHREADS, 0, stream>>>(src, dst, bcursor, staged, n_edges, cap);
    bucket_finalize<<<nb, CTHREADS, 0, stream>>>(bcursor, staged, cap, csr, meta,
                                                 feat, s[0], n_nodes);

    int n_quads = n_nodes * 4;
    int hop_blocks = (n_quads + 255) / 256;
    for (int k = 1; k < 4; ++k)
        hop_kernel<<<hop_blocks, 256, 0, stream>>>(meta, csr, s[k - 1], s[k], n_nodes);
    hop_last_kernel<<<hop_blocks, 256, 0, stream>>>(meta, csr,
                                                    s[1], s[2], s[3], feat, h, n_nodes);
}